// Round 2
// baseline (308.771 us; speedup 1.0000x reference)
//
#include <hip/hip_runtime.h>
#include <math.h>

#define N_MELS   128
#define N_FFT    2048
#define HOP      512
#define BATCH    8
#define S_LEN    661500
#define CH       2
#define T_FRAMES 1292            // 1 + S_LEN/HOP
#define NC       1024            // complex FFT length (N_FFT/2)
#define PAD      1024            // N_FFT/2 reflect pad
#define NBINS    1025            // 1 + N_FFT/2

// LDS skew: stride-17 over 16-element groups -> bit-reverse writes (multiples
// of 16 across a wave) land on distinct banks (17 coprime 32).
// Macro so it's a constant expression for __shared__ array sizes.
#define SK(j) ((j) + ((j) >> 4))

#define ANG 0.003067961575771282f   // 2*pi/2048 == pi/1024

// --- setup: find per-mel nonzero [start,end) ranges (sparse triangles) ---
__global__ __launch_bounds__(128) void mel_ranges_kernel(
        const float* __restrict__ fb, int* __restrict__ ranges) {
    int m = threadIdx.x;
    if (m >= N_MELS) return;
    const float* row = fb + m * NBINS;
    int s = NBINS, e = 0;
    for (int f = 0; f < NBINS; ++f) {
        float w = row[f];
        if (w != 0.0f) { if (f < s) s = f; e = f + 1; }
    }
    if (s > e) { s = 0; e = 0; }
    ranges[2 * m]     = s;
    ranges[2 * m + 1] = e;
}

// --- main: one block per (b, c, t) frame ---
__global__ __launch_bounds__(256) void mel_spec_kernel(
        const float* __restrict__ x, const float* __restrict__ fb,
        const int* __restrict__ ranges, float* __restrict__ out) {
    __shared__ float zr[SK(NC - 1) + 1];     // 1087 floats
    __shared__ float zi[SK(NC - 1) + 1];
    __shared__ float twr[SK(NC / 2 - 1) + 1]; // 543 floats
    __shared__ float twi[SK(NC / 2 - 1) + 1];
    __shared__ float pw[NBINS];

    const int tid = threadIdx.x;
    const int fid = blockIdx.x;
    const int t   = fid % T_FRAMES;
    const int rem = fid / T_FRAMES;
    const int c   = rem & 1;
    const int b   = rem >> 1;

    const float* xb = x + ((size_t)b * S_LEN) * CH + c;

    // Load 2048 windowed samples packed as 1024 complex, bit-reversed placement.
    for (int k = tid; k < NC; k += 256) {
        int n0 = 2 * k, n1 = 2 * k + 1;
        int s0 = t * HOP + n0 - PAD;
        int s1 = s0 + 1;
        if (s0 < 0) s0 = -s0; else if (s0 >= S_LEN) s0 = 2 * S_LEN - 2 - s0;
        if (s1 < 0) s1 = -s1; else if (s1 >= S_LEN) s1 = 2 * S_LEN - 2 - s1;
        float w0 = 0.5f - 0.5f * cosf(ANG * (float)n0);
        float w1 = 0.5f - 0.5f * cosf(ANG * (float)n1);
        float v0 = xb[(size_t)s0 * CH] * w0;
        float v1 = xb[(size_t)s1 * CH] * w1;
        int j = (int)(__brev((unsigned)k) >> 22);   // 10-bit bit-reverse
        zr[SK(j)] = v0;
        zi[SK(j)] = v1;
    }
    // Twiddle table: tw[j] = exp(-2*pi*i*j/1024), j in [0,512)
    for (int j = tid; j < NC / 2; j += 256) {
        float sn, cs;
        sincosf(-2.0f * ANG * (float)j, &sn, &cs);
        twr[SK(j)] = cs;
        twi[SK(j)] = sn;
    }

    // Radix-2 DIT, 10 stages.
    for (int st = 1; st <= 10; ++st) {
        __syncthreads();
        const int half   = 1 << (st - 1);
        const int tshift = 10 - st;
        #pragma unroll
        for (int ii = 0; ii < 2; ++ii) {
            int i = tid + ii * 256;
            int pos = i & (half - 1);
            int i1  = ((i >> (st - 1)) << st) + pos;
            int i2  = i1 + half;
            int twidx = pos << tshift;
            float wr = twr[SK(twidx)], wi = twi[SK(twidx)];
            float arr = zr[SK(i1)], aii = zi[SK(i1)];
            float brr = zr[SK(i2)], bii = zi[SK(i2)];
            float tr = wr * brr - wi * bii;
            float ti = wr * bii + wi * brr;
            zr[SK(i1)] = arr + tr;
            zi[SK(i1)] = aii + ti;
            zr[SK(i2)] = arr - tr;
            zi[SK(i2)] = aii - ti;
        }
    }
    __syncthreads();

    // Real-FFT untangle + power spectrum.
    for (int f = tid; f < NBINS; f += 256) {
        int fa = f & (NC - 1);
        int fm = (NC - f) & (NC - 1);
        float ar = zr[SK(fa)], ai = zi[SK(fa)];
        float br = zr[SK(fm)], bi = -zi[SK(fm)];
        float xer = 0.5f * (ar + br);
        float xei = 0.5f * (ai + bi);
        float xor_ = 0.5f * (ai - bi);
        float xoi  = -0.5f * (ar - br);
        float sn, cs;
        sincosf(-ANG * (float)f, &sn, &cs);   // exp(-2*pi*i*f/2048)
        float xr = xer + cs * xor_ - sn * xoi;
        float xi_ = xei + cs * xoi + sn * xor_;
        pw[f] = xr * xr + xi_ * xi_;
    }
    __syncthreads();

    // Sparse mel projection: threads 0..127, one mel each.
    if (tid < N_MELS) {
        int m  = tid;
        int s0 = ranges[2 * m];
        int e0 = ranges[2 * m + 1];
        const float* row = fb + m * NBINS;
        float acc = 0.0f;
        for (int f = s0; f < e0; ++f) acc += row[f] * pw[f];
        out[(((size_t)b * N_MELS + m) * T_FRAMES + t) * CH + c] = acc;
    }
}

extern "C" void kernel_launch(void* const* d_in, const int* in_sizes, int n_in,
                              void* d_out, int out_size, void* d_ws, size_t ws_size,
                              hipStream_t stream) {
    const float* x  = (const float*)d_in[0];
    const float* fb = (const float*)d_in[1];
    float* out = (float*)d_out;
    int* ranges = (int*)d_ws;

    mel_ranges_kernel<<<1, 128, 0, stream>>>(fb, ranges);
    mel_spec_kernel<<<BATCH * CH * T_FRAMES, 256, 0, stream>>>(x, fb, ranges, out);
}

// Round 3
// 250.546 us; speedup vs baseline: 1.2324x; 1.2324x over previous
//
#include <hip/hip_runtime.h>
#include <math.h>

#define N_MELS   128
#define N_FFT    2048
#define HOP      512
#define BATCH    8
#define S_LEN    661500
#define CH       2
#define T_FRAMES 1292            // 1 + S_LEN/HOP
#define NC       1024            // complex FFT length (N_FFT/2)
#define PAD      1024            // N_FFT/2 reflect pad
#define NBINS    1025            // 1 + N_FFT/2

#define ANG 0.003067961575771282f   // 2*pi/2048 == pi/1024

// d_ws layout (byte offsets)
#define WS_WIN     0        // float[2048]
#define WS_TW      8192     // float2[1024]  W_1024^j = exp(-2*pi*i*j/1024)
#define WS_U       16384    // float2[1025]  exp(-2*pi*i*f/2048)
#define WS_RANGES  24584    // int[256]

__device__ __forceinline__ float2 cadd(float2 a, float2 b){ return make_float2(a.x+b.x, a.y+b.y); }
__device__ __forceinline__ float2 csub(float2 a, float2 b){ return make_float2(a.x-b.x, a.y-b.y); }
__device__ __forceinline__ float2 cmul(float2 a, float2 b){ return make_float2(a.x*b.x - a.y*b.y, a.x*b.y + a.y*b.x); }

// --- once-per-launch transcendental tables ---
__global__ __launch_bounds__(256) void tables_kernel(float* __restrict__ ws) {
    int i = blockIdx.x * 256 + threadIdx.x;
    float*  win = ws;
    float2* tw  = (float2*)((char*)ws + WS_TW);
    float2* u   = (float2*)((char*)ws + WS_U);
    if (i < N_FFT) win[i] = 0.5f - 0.5f * cosf(ANG * (float)i);
    if (i < NC)   { float sn, cs; sincosf(-2.0f * ANG * (float)i, &sn, &cs); tw[i] = make_float2(cs, sn); }
    if (i < NBINS){ float sn, cs; sincosf(-ANG * (float)i, &sn, &cs);        u[i]  = make_float2(cs, sn); }
}

// --- per-mel nonzero [start,end): one wave per mel, shuffle-reduced ---
__global__ __launch_bounds__(64) void mel_ranges_kernel(
        const float* __restrict__ fb, int* __restrict__ ranges) {
    int m = blockIdx.x;
    int lane = threadIdx.x;
    const float* row = fb + m * NBINS;
    int s = NBINS, e = -1;
    for (int f = lane; f < NBINS; f += 64) {
        if (row[f] != 0.0f) { if (f < s) s = f; if (f > e) e = f; }
    }
    #pragma unroll
    for (int o = 32; o; o >>= 1) {
        s = min(s, __shfl_xor(s, o));
        e = max(e, __shfl_xor(e, o));
    }
    if (lane == 0) {
        ranges[2*m]   = (e < 0) ? 0 : s;
        ranges[2*m+1] = e + 1;
    }
}

// Radix-4 Stockham DIF stage (OTFFT form), constant-geometry reads.
// T = stage index 0..4, s = 4^T.
#define STAGE(SRC, DST, T) { \
    const int s_    = 1 << (2*(T)); \
    const int mask_ = s_ - 1; \
    const int e1 = tid & ~mask_; \
    float2 a_ = SRC[tid], b_ = SRC[tid+256], c_ = SRC[tid+512], d_ = SRC[tid+768]; \
    float2 apc = cadd(a_, c_), amc = csub(a_, c_); \
    float2 bpd = cadd(b_, d_), bmd = csub(b_, d_); \
    float2 w1 = tw[e1], w2 = tw[2*e1], w3 = tw[3*e1]; \
    const int base = (tid & mask_) + 4*e1; \
    DST[base]        = cadd(apc, bpd); \
    DST[base + s_]   = cmul(w1, make_float2(amc.x + bmd.y, amc.y - bmd.x)); \
    DST[base + 2*s_] = cmul(w2, csub(apc, bpd)); \
    DST[base + 3*s_] = cmul(w3, make_float2(amc.x - bmd.y, amc.y + bmd.x)); \
    __syncthreads(); }

// --- main: one block per (b, c, t) frame ---
__global__ __launch_bounds__(256) void mel_spec_kernel(
        const float* __restrict__ x, const float* __restrict__ fb,
        const float* __restrict__ ws, float* __restrict__ out) {
    __shared__ float2 Abuf[NC];   // 8 KB
    __shared__ float2 Bbuf[NC];   // 8 KB
    float* pw = (float*)Abuf;     // power spectrum aliases Abuf (dead after stage 4)

    const float*  win    = ws;
    const float2* tw     = (const float2*)((const char*)ws + WS_TW);
    const float2* u      = (const float2*)((const char*)ws + WS_U);
    const int*    ranges = (const int*)((const char*)ws + WS_RANGES);

    const int tid = threadIdx.x;
    const int fid = blockIdx.x;
    const int t   = fid % T_FRAMES;
    const int rem = fid / T_FRAMES;
    const int c   = rem & 1;
    const int b   = rem >> 1;

    const float* xb = x + (size_t)b * S_LEN * CH;

    // Stage in natural order: z[k] = x[2k] + i*x[2k+1], windowed.
    // s0 = t*HOP - PAD + 2k is always even -> interior loads are one float4
    // (both samples, both channels on one 16B line).
    #pragma unroll
    for (int kk = 0; kk < 4; ++kk) {
        int k  = tid + 256*kk;
        int s0 = t*HOP - PAD + 2*k;
        float v0, v1;
        if (s0 >= 0 && s0 + 1 < S_LEN) {
            float4 v4 = ((const float4*)xb)[s0 >> 1];
            v0 = c ? v4.y : v4.x;
            v1 = c ? v4.w : v4.z;
        } else {
            int a0 = s0, a1 = s0 + 1;
            if (a0 < 0) a0 = -a0; else if (a0 >= S_LEN) a0 = 2*S_LEN - 2 - a0;
            if (a1 < 0) a1 = -a1; else if (a1 >= S_LEN) a1 = 2*S_LEN - 2 - a1;
            v0 = xb[(size_t)a0 * CH + c];
            v1 = xb[(size_t)a1 * CH + c];
        }
        float2 wv = ((const float2*)win)[k];
        Abuf[k] = make_float2(v0 * wv.x, v1 * wv.y);
    }
    __syncthreads();

    STAGE(Abuf, Bbuf, 0)
    STAGE(Bbuf, Abuf, 1)
    STAGE(Abuf, Bbuf, 2)
    STAGE(Bbuf, Abuf, 3)
    STAGE(Abuf, Bbuf, 4)
    // FFT result (natural order) now in Bbuf.

    // Real-FFT untangle + power spectrum (table-driven).
    for (int f = tid; f < NBINS; f += 256) {
        int fa = f & (NC - 1);
        int fm = (NC - f) & (NC - 1);
        float2 Zf = Bbuf[fa];
        float2 Zm = Bbuf[fm];
        float ar = Zf.x, ai = Zf.y;
        float br = Zm.x, bi = -Zm.y;
        float xer  = 0.5f * (ar + br);
        float xei  = 0.5f * (ai + bi);
        float xor_ = 0.5f * (ai - bi);
        float xoi  = -0.5f * (ar - br);
        float2 uf = u[f];
        float xr  = xer + uf.x * xor_ - uf.y * xoi;
        float xi_ = xei + uf.x * xoi + uf.y * xor_;
        pw[f] = xr * xr + xi_ * xi_;
    }
    __syncthreads();

    // Sparse mel projection: threads 0..127, one mel each.
    if (tid < N_MELS) {
        int m  = tid;
        int s0 = ranges[2*m];
        int e0 = ranges[2*m+1];
        const float* row = fb + m * NBINS;
        float acc = 0.0f;
        for (int f = s0; f < e0; ++f) acc += row[f] * pw[f];
        out[(((size_t)b * N_MELS + m) * T_FRAMES + t) * CH + c] = acc;
    }
}

extern "C" void kernel_launch(void* const* d_in, const int* in_sizes, int n_in,
                              void* d_out, int out_size, void* d_ws, size_t ws_size,
                              hipStream_t stream) {
    const float* x  = (const float*)d_in[0];
    const float* fb = (const float*)d_in[1];
    float* out = (float*)d_out;
    float* ws  = (float*)d_ws;
    int* ranges = (int*)((char*)d_ws + WS_RANGES);

    tables_kernel<<<8, 256, 0, stream>>>(ws);
    mel_ranges_kernel<<<N_MELS, 64, 0, stream>>>(fb, ranges);
    mel_spec_kernel<<<BATCH * CH * T_FRAMES, 256, 0, stream>>>(x, fb, ws, out);
}

// Round 4
// 213.192 us; speedup vs baseline: 1.4483x; 1.1752x over previous
//
#include <hip/hip_runtime.h>
#include <math.h>

#define N_MELS   128
#define N_FFT    2048
#define HOP      512
#define BATCH    8
#define S_LEN    661500
#define CH       2
#define T_FRAMES 1292            // 1 + S_LEN/HOP
#define NBINS    1025            // 1 + N_FFT/2

#define ANG 0.003067961575771282f   // 2*pi/2048

// d_ws layout (byte offsets)
#define WS_WIN     0        // float[2048]   hann window
#define WS_TW      8192     // float2[2048]  W_2048^j = exp(-2*pi*i*j/2048)
#define WS_RANGES  24576    // int[256]      per-mel [start,end)

#define PW_STRIDE  1056     // pw[c*1056 + f], 1056 = 33*32

__device__ __forceinline__ float2 cadd(float2 a, float2 b){ return make_float2(a.x+b.x, a.y+b.y); }
__device__ __forceinline__ float2 csub(float2 a, float2 b){ return make_float2(a.x-b.x, a.y-b.y); }
__device__ __forceinline__ float2 cmul(float2 a, float2 b){ return make_float2(a.x*b.x - a.y*b.y, a.x*b.y + a.y*b.x); }

// --- merged setup: blocks 0..7 build tables, blocks 8..135 scan one mel row each ---
__global__ __launch_bounds__(256) void setup_kernel(
        const float* __restrict__ fb, float* __restrict__ ws) {
    int blk = blockIdx.x;
    if (blk < 8) {
        int i = blk * 256 + threadIdx.x;          // i in [0,2048)
        float*  win = ws;
        float2* tw  = (float2*)((char*)ws + WS_TW);
        win[i] = 0.5f - 0.5f * cosf(ANG * (float)i);
        float sn, cs; sincosf(-ANG * (float)i, &sn, &cs);
        tw[i] = make_float2(cs, sn);
    } else {
        int m = blk - 8;
        int lane = threadIdx.x;
        if (lane < 64) {
            int* ranges = (int*)((char*)ws + WS_RANGES);
            const float* row = fb + m * NBINS;
            int s = NBINS, e = -1;
            for (int f = lane; f < NBINS; f += 64) {
                if (row[f] != 0.0f) { if (f < s) s = f; if (f > e) e = f; }
            }
            #pragma unroll
            for (int o = 32; o; o >>= 1) {
                s = min(s, __shfl_xor(s, o));
                e = max(e, __shfl_xor(e, o));
            }
            if (lane == 0) {
                ranges[2*m]   = (e < 0) ? 0 : s;
                ranges[2*m+1] = e + 1;
            }
        }
    }
}

// Radix-4 Stockham DIF stage for N=2048, 512 threads (one butterfly each).
// Stage T: s = 4^T. Reads SRC[i + j*512]; writes DST[(i&mask) + 4*(i&~mask) + j*s],
// twiddle W_2048^{j*s*p} with s*p = i&~mask.  (OTFFT recursion form.)
#define STAGE(SRC, DST, T) { \
    const int s_    = 1 << (2*(T)); \
    const int mask_ = s_ - 1; \
    const int e1 = tid & ~mask_; \
    float2 a_ = SRC[tid], b_ = SRC[tid+512], c_ = SRC[tid+1024], d_ = SRC[tid+1536]; \
    float2 apc = cadd(a_, c_), amc = csub(a_, c_); \
    float2 bpd = cadd(b_, d_), bmd = csub(b_, d_); \
    float2 w1 = tw[e1], w2 = tw[2*e1], w3 = tw[3*e1]; \
    const int base = (tid & mask_) + 4*e1; \
    DST[base]        = cadd(apc, bpd); \
    DST[base + s_]   = cmul(w1, make_float2(amc.x + bmd.y, amc.y - bmd.x)); \
    DST[base + 2*s_] = cmul(w2, csub(apc, bpd)); \
    DST[base + 3*s_] = cmul(w3, make_float2(amc.x - bmd.y, amc.y + bmd.x)); \
    __syncthreads(); }

// --- main: one block per (b, t) frame; both channels via one complex FFT ---
__global__ __launch_bounds__(512) void mel_spec_kernel(
        const float* __restrict__ x, const float* __restrict__ fb,
        const float* __restrict__ ws, float* __restrict__ out) {
    __shared__ float2 Abuf[N_FFT];   // 16 KB
    __shared__ float2 Bbuf[N_FFT];   // 16 KB
    float* pw = (float*)Bbuf;        // pw[c*1056+f] aliases Bbuf (dead after radix-2)

    const float*  win    = ws;
    const float2* tw     = (const float2*)((const char*)ws + WS_TW);
    const int*    ranges = (const int*)((const char*)ws + WS_RANGES);

    const int tid = threadIdx.x;
    const int fid = blockIdx.x;
    const int t   = fid % T_FRAMES;
    const int b   = fid / T_FRAMES;

    const float2* xb = (const float2*)x + (size_t)b * S_LEN;   // (c0,c1) pairs

    // Stage: z[n] = (c0[n] + i*c1[n]) * win[n], natural order, coalesced float2.
    #pragma unroll
    for (int kk = 0; kk < 4; ++kk) {
        int n  = tid + 512*kk;
        int s0 = t*HOP - (N_FFT/2) + n;
        if (s0 < 0) s0 = -s0; else if (s0 >= S_LEN) s0 = 2*S_LEN - 2 - s0;
        float2 v = xb[s0];
        float  w = win[n];
        Abuf[n] = make_float2(v.x * w, v.y * w);
    }
    __syncthreads();

    STAGE(Abuf, Bbuf, 0)
    STAGE(Bbuf, Abuf, 1)
    STAGE(Abuf, Bbuf, 2)
    STAGE(Bbuf, Abuf, 3)
    STAGE(Abuf, Bbuf, 4)
    // Final radix-2 stage (s=1024, twiddle-free): Bbuf -> Abuf, natural order out.
    {
        float2 a0 = Bbuf[tid],       b0 = Bbuf[tid+1024];
        float2 a1 = Bbuf[tid+512],   b1 = Bbuf[tid+1536];
        __syncthreads();             // Bbuf reads done before pw aliasing writes later
        Abuf[tid]        = cadd(a0, b0);
        Abuf[tid+1024]   = csub(a0, b0);
        Abuf[tid+512]    = cadd(a1, b1);
        Abuf[tid+1536]   = csub(a1, b1);
        __syncthreads();
    }

    // Two-channel untangle + power (twiddle-free):
    // A[f] = (Z[f]+conj(Z[N-f]))/2, B[f] = (Z[f]-conj(Z[N-f]))/(2i)
    #pragma unroll
    for (int it = 0; it < 2; ++it) {
        int f = tid + 512*it;
        if (f <= 1024) {
            float2 Zf = Abuf[f];
            float2 Zm = Abuf[(N_FFT - f) & (N_FFT - 1)];
            float br = Zm.x, bi = -Zm.y;
            float e0 = Zf.x + br, e1 = Zf.y + bi;
            float o0 = Zf.y - bi, o1 = Zf.x - br;
            pw[f]             = 0.25f * (e0*e0 + e1*e1);   // |A|^2, channel 0
            pw[PW_STRIDE + f] = 0.25f * (o0*o0 + o1*o1);   // |B|^2, channel 1
        }
    }
    __syncthreads();

    // Sparse mel projection: threads 0..255, (m,c) = (tid>>1, tid&1).
    if (tid < 256) {
        int m = tid >> 1;
        int c = tid & 1;
        int s0 = ranges[2*m];
        int e0 = ranges[2*m+1];
        const float* row = fb + m * NBINS;
        const float* pwc = pw + c * PW_STRIDE;
        float acc = 0.0f;
        for (int f = s0; f < e0; ++f) acc += row[f] * pwc[f];
        out[(((size_t)b * N_MELS + m) * T_FRAMES + t) * CH + c] = acc;
    }
}

extern "C" void kernel_launch(void* const* d_in, const int* in_sizes, int n_in,
                              void* d_out, int out_size, void* d_ws, size_t ws_size,
                              hipStream_t stream) {
    const float* x  = (const float*)d_in[0];
    const float* fb = (const float*)d_in[1];
    float* out = (float*)d_out;
    float* ws  = (float*)d_ws;

    setup_kernel<<<8 + N_MELS, 256, 0, stream>>>(fb, ws);
    mel_spec_kernel<<<BATCH * T_FRAMES, 512, 0, stream>>>(x, fb, ws, out);
}

// Round 5
// 212.105 us; speedup vs baseline: 1.4557x; 1.0051x over previous
//
#include <hip/hip_runtime.h>
#include <math.h>

#define N_MELS   128
#define N_FFT    2048
#define HOP      512
#define BATCH    8
#define S_LEN    661500
#define CH       2
#define T_FRAMES 1292            // 1 + S_LEN/HOP
#define NBINS    1025            // 1 + N_FFT/2

#define ANG 0.003067961575771282f   // 2*pi/2048

// d_ws layout (byte offsets)
#define WS_WIN     0        // float[2048]   hann window
#define WS_TW      8192     // float2[2048]  W_2048^j = exp(-2*pi*i*j/2048)
#define WS_RANGES  24576    // int[256]      per-mel [start,end)

#define PW_STRIDE  1056     // pw[c*1056 + f]

__device__ __forceinline__ float2 cadd(float2 a, float2 b){ return make_float2(a.x+b.x, a.y+b.y); }
__device__ __forceinline__ float2 csub(float2 a, float2 b){ return make_float2(a.x-b.x, a.y-b.y); }
__device__ __forceinline__ float2 cmul(float2 a, float2 b){ return make_float2(a.x*b.x - a.y*b.y, a.x*b.y + a.y*b.x); }

// radix-4 DIF butterfly (OTFFT form), twiddles applied to outputs 1..3
__device__ __forceinline__ void bfly4(float2 a, float2 b, float2 c, float2 d,
                                      float2 w1, float2 w2, float2 w3,
                                      float2& o0, float2& o1, float2& o2, float2& o3) {
    float2 apc = cadd(a, c), amc = csub(a, c);
    float2 bpd = cadd(b, d), bmd = csub(b, d);
    o0 = cadd(apc, bpd);
    o1 = cmul(w1, make_float2(amc.x + bmd.y, amc.y - bmd.x));
    o2 = cmul(w2, csub(apc, bpd));
    o3 = cmul(w3, make_float2(amc.x - bmd.y, amc.y + bmd.x));
}

// two-channel untangle: returns (|A|^2, |B|^2) for Zf, Zm=Z[N-f]
__device__ __forceinline__ float2 upair(float2 Zf, float2 Zm) {
    float br = Zm.x, bi = -Zm.y;
    float e0 = Zf.x + br, e1 = Zf.y + bi;
    float o0 = Zf.y - bi, o1 = Zf.x - br;
    return make_float2(0.25f*(e0*e0 + e1*e1), 0.25f*(o0*o0 + o1*o1));
}

// --- merged setup: blocks 0..7 build tables, blocks 8..135 scan one mel row each ---
__global__ __launch_bounds__(256) void setup_kernel(
        const float* __restrict__ fb, float* __restrict__ ws) {
    int blk = blockIdx.x;
    if (blk < 8) {
        int i = blk * 256 + threadIdx.x;          // i in [0,2048)
        float*  win = ws;
        float2* tw  = (float2*)((char*)ws + WS_TW);
        win[i] = 0.5f - 0.5f * cosf(ANG * (float)i);
        float sn, cs; sincosf(-ANG * (float)i, &sn, &cs);
        tw[i] = make_float2(cs, sn);
    } else {
        int m = blk - 8;
        int lane = threadIdx.x;
        if (lane < 64) {
            int* ranges = (int*)((char*)ws + WS_RANGES);
            const float* row = fb + m * NBINS;
            int s = NBINS, e = -1;
            for (int f = lane; f < NBINS; f += 64) {
                if (row[f] != 0.0f) { if (f < s) s = f; if (f > e) e = f; }
            }
            #pragma unroll
            for (int o = 32; o; o >>= 1) {
                s = min(s, __shfl_xor(s, o));
                e = max(e, __shfl_xor(e, o));
            }
            if (lane == 0) {
                ranges[2*m]   = (e < 0) ? 0 : s;
                ranges[2*m+1] = e + 1;
            }
        }
    }
}

// Paired-butterfly radix-4 Stockham stage, T>=1 (both butterflies share twiddles).
// Butterflies i0=2*tid, i0+1; all LDS traffic is float4 (2 complex).
#define STAGEP(SRC4, DST4, T) { \
    const int s_    = 1 << (2*(T)); \
    const int mask_ = s_ - 1; \
    const int i0 = 2*tid; \
    const int e1 = i0 & ~mask_; \
    float4 ra = SRC4[tid], rb = SRC4[tid+256], rc = SRC4[tid+512], rd = SRC4[tid+768]; \
    float2 w1 = tw[e1], w2 = tw[2*e1], w3 = tw[3*e1]; \
    float2 o0l,o1l,o2l,o3l,o0h,o1h,o2h,o3h; \
    bfly4(make_float2(ra.x,ra.y), make_float2(rb.x,rb.y), make_float2(rc.x,rc.y), make_float2(rd.x,rd.y), w1,w2,w3, o0l,o1l,o2l,o3l); \
    bfly4(make_float2(ra.z,ra.w), make_float2(rb.z,rb.w), make_float2(rc.z,rc.w), make_float2(rd.z,rd.w), w1,w2,w3, o0h,o1h,o2h,o3h); \
    const int h = ((i0 & mask_) + 4*e1) >> 1; \
    DST4[h]             = make_float4(o0l.x,o0l.y,o0h.x,o0h.y); \
    DST4[h + (s_>>1)]   = make_float4(o1l.x,o1l.y,o1h.x,o1h.y); \
    DST4[h + s_]        = make_float4(o2l.x,o2l.y,o2h.x,o2h.y); \
    DST4[h + 3*(s_>>1)] = make_float4(o3l.x,o3l.y,o3h.x,o3h.y); \
    __syncthreads(); }

// --- main: one block per (b, t) frame; XCD-contiguous swizzle b=bid&7 ---
__global__ __launch_bounds__(256) void mel_spec_kernel(
        const float* __restrict__ x, const float* __restrict__ fb,
        const float* __restrict__ ws, float* __restrict__ out) {
    __shared__ float2 Abuf[N_FFT];   // 16 KB
    __shared__ float2 Bbuf[N_FFT];   // 16 KB
    float4* A4 = (float4*)Abuf;
    float4* B4 = (float4*)Bbuf;
    float*  pw = (float*)Bbuf;       // aliases Bbuf (dead after radix-2)

    const float2* win2   = (const float2*)ws;
    const float2* tw     = (const float2*)((const char*)ws + WS_TW);
    const float4* tw4    = (const float4*)tw;
    const int*    ranges = (const int*)((const char*)ws + WS_RANGES);

    const int tid = threadIdx.x;
    const int bid = blockIdx.x;
    const int b   = bid & 7;          // XCD-contiguous: one batch item per XCD
    const int t   = bid >> 3;

    const float2* xb  = (const float2*)x + (size_t)b * S_LEN;   // (c0,c1) pairs
    const float4* xb4 = (const float4*)xb;
    const int tb = t*HOP - (N_FFT/2);

    // Stage: z[n] = (c0[n] + i*c1[n]) * win[n]; float4 = 2 samples.
    #pragma unroll
    for (int kk = 0; kk < 4; ++kk) {
        int p  = tid + 256*kk;        // sample-pair index: n = 2p, 2p+1
        int sp = tb + 2*p;
        float2 v0, v1;
        if (sp >= 0 && sp + 1 < S_LEN) {
            float4 v4 = xb4[sp >> 1];  // sp is even
            v0 = make_float2(v4.x, v4.y);
            v1 = make_float2(v4.z, v4.w);
        } else {
            int a0 = sp, a1 = sp + 1;
            if (a0 < 0) a0 = -a0; else if (a0 >= S_LEN) a0 = 2*S_LEN - 2 - a0;
            if (a1 < 0) a1 = -a1; else if (a1 >= S_LEN) a1 = 2*S_LEN - 2 - a1;
            v0 = xb[a0]; v1 = xb[a1];
        }
        float2 w = win2[p];
        A4[p] = make_float4(v0.x*w.x, v0.y*w.x, v1.x*w.y, v1.y*w.y);
    }
    __syncthreads();

    // Stage T=0 (s=1, per-butterfly twiddles; writes are 4 contiguous float4s).
    {
        const int i1 = 2*tid + 1;
        float4 ra = A4[tid], rb = A4[tid+256], rc = A4[tid+512], rd = A4[tid+768];
        float4 t01 = tw4[tid];                        // tw[2t], tw[2t+1]
        float4 t2a = tw4[2*tid], t2b = tw4[2*tid+1];  // tw[4t..4t+3]
        float4 t3a = tw4[3*tid], t3b = tw4[3*tid+1];  // tw[6t..6t+3]
        (void)i1;
        float2 o0l,o1l,o2l,o3l,o0h,o1h,o2h,o3h;
        bfly4(make_float2(ra.x,ra.y), make_float2(rb.x,rb.y), make_float2(rc.x,rc.y), make_float2(rd.x,rd.y),
              make_float2(t01.x,t01.y), make_float2(t2a.x,t2a.y), make_float2(t3a.x,t3a.y),
              o0l,o1l,o2l,o3l);
        bfly4(make_float2(ra.z,ra.w), make_float2(rb.z,rb.w), make_float2(rc.z,rc.w), make_float2(rd.z,rd.w),
              make_float2(t01.z,t01.w), make_float2(t2b.x,t2b.y), make_float2(t3b.z,t3b.w),
              o0h,o1h,o2h,o3h);
        B4[4*tid]   = make_float4(o0l.x,o0l.y,o1l.x,o1l.y);
        B4[4*tid+1] = make_float4(o2l.x,o2l.y,o3l.x,o3l.y);
        B4[4*tid+2] = make_float4(o0h.x,o0h.y,o1h.x,o1h.y);
        B4[4*tid+3] = make_float4(o2h.x,o2h.y,o3h.x,o3h.y);
        __syncthreads();
    }

    STAGEP(B4, A4, 1)
    STAGEP(A4, B4, 2)
    STAGEP(B4, A4, 3)
    STAGEP(A4, B4, 4)

    // Final radix-2 (s=1024, twiddle-free): B -> A, natural order out.
    #pragma unroll
    for (int it = 0; it < 2; ++it) {
        int v = tid + 256*it;          // v in [0,512): elements 2v,2v+1 and +1024
        float4 ya = B4[v], yb = B4[v+512];
        A4[v]     = make_float4(ya.x+yb.x, ya.y+yb.y, ya.z+yb.z, ya.w+yb.w);
        A4[v+512] = make_float4(ya.x-yb.x, ya.y-yb.y, ya.z-yb.z, ya.w-yb.w);
    }
    __syncthreads();

    // Untangle + power, pairs f=2v,2v+1 (v in [0,512)); pw aliases Bbuf.
    #pragma unroll
    for (int it = 0; it < 2; ++it) {
        int v = tid + 256*it;
        float4 F  = A4[v];                   // Z[2v], Z[2v+1]
        float4 Ma = A4[1023 - v];            // Z[2046-2v], Z[2047-2v]
        float4 Mb = A4[(1024 - v) & 1023];   // Z[2048-2v], Z[2049-2v] (v=0 -> Z[0],Z[1])
        float2 plo = upair(make_float2(F.x,F.y), make_float2(Mb.x,Mb.y)); // f=2v
        float2 phi = upair(make_float2(F.z,F.w), make_float2(Ma.z,Ma.w)); // f=2v+1
        ((float2*)pw)[v]               = make_float2(plo.x, phi.x);  // ch0: pw[2v], pw[2v+1]
        ((float2*)(pw + PW_STRIDE))[v] = make_float2(plo.y, phi.y);  // ch1
    }
    if (tid == 0) {
        float4 F = A4[512];                  // Z[1024]
        float2 p = upair(make_float2(F.x,F.y), make_float2(F.x,F.y));
        pw[1024]             = p.x;
        pw[PW_STRIDE + 1024] = p.y;
    }
    __syncthreads();

    // Sparse mel projection: (m,c) = (tid>>1, tid&1).
    {
        int m = tid >> 1;
        int c = tid & 1;
        int s0 = ranges[2*m];
        int e0 = ranges[2*m+1];
        const float* row = fb + m * NBINS;
        const float* pwc = pw + c * PW_STRIDE;
        float acc = 0.0f;
        for (int f = s0; f < e0; ++f) acc += row[f] * pwc[f];
        out[(((size_t)b * N_MELS + m) * T_FRAMES + t) * CH + c] = acc;
    }
}

extern "C" void kernel_launch(void* const* d_in, const int* in_sizes, int n_in,
                              void* d_out, int out_size, void* d_ws, size_t ws_size,
                              hipStream_t stream) {
    const float* x  = (const float*)d_in[0];
    const float* fb = (const float*)d_in[1];
    float* out = (float*)d_out;
    float* ws  = (float*)d_ws;

    setup_kernel<<<8 + N_MELS, 256, 0, stream>>>(fb, ws);
    mel_spec_kernel<<<BATCH * T_FRAMES, 256, 0, stream>>>(x, fb, ws, out);
}

// Round 6
// 161.662 us; speedup vs baseline: 1.9100x; 1.3120x over previous
//
#include <hip/hip_runtime.h>
#include <math.h>

#define N_MELS   128
#define N_FFT    2048
#define HOP      512
#define BATCH    8
#define S_LEN    661500
#define CH       2
#define T_FRAMES 1292            // 1 + S_LEN/HOP
#define NBINS    1025            // 1 + N_FFT/2

#define ANG 0.003067961575771282f   // 2*pi/2048

// d_ws layout (byte offsets)
#define WS_WIN     0        // float[2048]   hann window
#define WS_TW      8192     // float2[2048]  W_2048^j
#define WS_RANGES  24576    // int[256]      per-mel [start,end)

#define PW_STRIDE  1056     // pw[c*1056 + f] (aliases Z buffer, in floats)

__device__ __forceinline__ float2 cadd(float2 a, float2 b){ return make_float2(a.x+b.x, a.y+b.y); }
__device__ __forceinline__ float2 csub(float2 a, float2 b){ return make_float2(a.x-b.x, a.y-b.y); }
__device__ __forceinline__ float2 cmul(float2 a, float2 b){ return make_float2(a.x*b.x - a.y*b.y, a.x*b.y + a.y*b.x); }
__device__ __forceinline__ float2 cnegi(float2 z){ return make_float2(z.y, -z.x); }   // -i*z

// padded LDS layout: complex element e lives at Z[e + (e>>3)]
__device__ __forceinline__ int OFF(int e){ return e + (e >> 3); }

// radix-8 DIF butterfly: b[k] = sum_j a[j] * W8^{jk}, W8 = exp(-i*pi/4)
__device__ __forceinline__ void bfly8(const float2* a, float2* b) {
    const float C = 0.70710678118654752f;
    float2 e0=cadd(a[0],a[4]), e1=cadd(a[1],a[5]), e2=cadd(a[2],a[6]), e3=cadd(a[3],a[7]);
    float2 o0=csub(a[0],a[4]), o1=csub(a[1],a[5]), o2=csub(a[2],a[6]), o3=csub(a[3],a[7]);
    float2 t1 = make_float2(C*(o1.x+o1.y), C*(o1.y-o1.x));      // o1*W8^1
    float2 t2 = make_float2(o2.y, -o2.x);                        // o2*W8^2 (-i)
    float2 t3 = make_float2(C*(o3.y-o3.x), -C*(o3.x+o3.y));      // o3*W8^3
    { // DFT4 on evens -> b0,b2,b4,b6
        float2 s0=cadd(e0,e2), d0=csub(e0,e2);
        float2 s1=cadd(e1,e3), d1=csub(e1,e3);
        b[0]=cadd(s0,s1); b[4]=csub(s0,s1);
        b[2]=cadd(d0,cnegi(d1)); b[6]=csub(d0,cnegi(d1));
    }
    { // DFT4 on twiddled odds -> b1,b3,b5,b7
        float2 s0=cadd(o0,t2), d0=csub(o0,t2);
        float2 s1=cadd(t1,t3), d1=csub(t1,t3);
        b[1]=cadd(s0,s1); b[5]=csub(s0,s1);
        b[3]=cadd(d0,cnegi(d1)); b[7]=csub(d0,cnegi(d1));
    }
}

// two-channel untangle: (|A|^2, |B|^2) for Zf, Zm = Z[N-f]
__device__ __forceinline__ float2 upair(float2 Zf, float2 Zm) {
    float br = Zm.x, bi = -Zm.y;
    float e0 = Zf.x + br, e1 = Zf.y + bi;
    float o0 = Zf.y - bi, o1 = Zf.x - br;
    return make_float2(0.25f*(e0*e0 + e1*e1), 0.25f*(o0*o0 + o1*o1));
}

// --- merged setup: blocks 0..7 build tables, blocks 8..135 scan one mel row each ---
__global__ __launch_bounds__(256) void setup_kernel(
        const float* __restrict__ fb, float* __restrict__ ws) {
    int blk = blockIdx.x;
    if (blk < 8) {
        int i = blk * 256 + threadIdx.x;
        float*  win = ws;
        float2* tw  = (float2*)((char*)ws + WS_TW);
        win[i] = 0.5f - 0.5f * cosf(ANG * (float)i);
        float sn, cs; sincosf(-ANG * (float)i, &sn, &cs);
        tw[i] = make_float2(cs, sn);
    } else {
        int m = blk - 8;
        int lane = threadIdx.x;
        if (lane < 64) {
            int* ranges = (int*)((char*)ws + WS_RANGES);
            const float* row = fb + m * NBINS;
            int s = NBINS, e = -1;
            for (int f = lane; f < NBINS; f += 64) {
                if (row[f] != 0.0f) { if (f < s) s = f; if (f > e) e = f; }
            }
            #pragma unroll
            for (int o = 32; o; o >>= 1) {
                s = min(s, __shfl_xor(s, o));
                e = max(e, __shfl_xor(e, o));
            }
            if (lane == 0) {
                ranges[2*m]   = (e < 0) ? 0 : s;
                ranges[2*m+1] = e + 1;
            }
        }
    }
}

// --- main: register radix-8 FFT (2048 = 8*8*8*4), one block per (b,t) frame ---
__global__ __launch_bounds__(256, 8) void mel_spec_kernel(
        const float* __restrict__ x, const float* __restrict__ fb,
        const float* __restrict__ ws, float* __restrict__ out) {
    __shared__ float2 Z[N_FFT + N_FFT/8];   // 2304 float2 = 18 KB, padded layout
    float* pw = (float*)Z;                   // reused after untangle reads

    const float*  win    = ws;
    const float2* tw     = (const float2*)((const char*)ws + WS_TW);
    const int*    ranges = (const int*)((const char*)ws + WS_RANGES);

    const int tid = threadIdx.x;
    const int bid = blockIdx.x;
    const int b   = bid & 7;          // XCD-contiguous: one batch item per XCD
    const int t   = bid >> 3;

    const float2* xb = (const float2*)x + (size_t)b * S_LEN;
    const int tb = t*HOP - (N_FFT/2);

    float2 r[8], bq[8];

    // Stage 0 input: thread holds x[tid + 256k] (windowed), coalesced loads.
    #pragma unroll
    for (int k = 0; k < 8; ++k) {
        int n  = tid + 256*k;
        int s0 = tb + n;
        if (s0 < 0) s0 = -s0; else if (s0 >= S_LEN) s0 = 2*S_LEN - 2 - s0;
        float2 v = xb[s0];
        float  w = win[n];
        r[k] = make_float2(v.x*w, v.y*w);
    }

    // ---- Stage 1: radix-8, s=1, e1 = tid. Twiddle W^{k*tid} incremental.
    bfly8(r, bq);
    {
        float2 w1 = tw[tid];
        int base = 9*tid;                     // OFF(8*tid + k) = 9*tid + k
        Z[base] = bq[0];
        float2 wk = w1;
        #pragma unroll
        for (int k = 1; k < 8; ++k) {
            Z[base + k] = cmul(wk, bq[k]);
            wk = cmul(wk, w1);
        }
    }
    __syncthreads();

    // ---- Stage 2: radix-8, s=8. Read e = tid + 256k.
    #pragma unroll
    for (int k = 0; k < 8; ++k) r[k] = Z[tid + (tid>>3) + 288*k];
    __syncthreads();
    bfly8(r, bq);
    {
        float2 w1 = tw[tid & ~7];
        int q = tid & 7, a = tid >> 3;
        int base = q + 72*a;                  // OFF(q + 64a + 8k) = q + 72a + 9k
        Z[base] = bq[0];
        float2 wk = w1;
        #pragma unroll
        for (int k = 1; k < 8; ++k) {
            Z[base + 9*k] = cmul(wk, bq[k]);
            wk = cmul(wk, w1);
        }
    }
    __syncthreads();

    // ---- Stage 3: radix-8, s=64. Read e = tid + 256k.
    #pragma unroll
    for (int k = 0; k < 8; ++k) r[k] = Z[tid + (tid>>3) + 288*k];
    __syncthreads();
    bfly8(r, bq);
    {
        float2 w1 = tw[tid & ~63];
        int q = tid & 63, a = tid >> 6;
        int base = q + (q>>3) + 576*a;        // OFF(q + 512a + 64k) = base + 72k
        Z[base] = bq[0];
        float2 wk = w1;
        #pragma unroll
        for (int k = 1; k < 8; ++k) {
            Z[base + 72*k] = cmul(wk, bq[k]);
            wk = cmul(wk, w1);
        }
    }
    __syncthreads();

    // ---- Stage 4: radix-4, s=512, twiddle-free. Butterflies i' = tid, tid+256.
    // Reads and writes the SAME addresses e = i' + 512k -> no exchange barrier.
    #pragma unroll
    for (int half = 0; half < 2; ++half) {
        int ip   = tid + 256*half;
        int base = ip + (ip>>3);              // OFF(ip + 512k) = base + 576k
        float2 a0 = Z[base], a1 = Z[base+576], a2 = Z[base+1152], a3 = Z[base+1728];
        float2 apc = cadd(a0,a2), amc = csub(a0,a2);
        float2 bpd = cadd(a1,a3), bmd = csub(a1,a3);
        Z[base]      = cadd(apc, bpd);
        Z[base+576]  = cadd(amc, cnegi(bmd));
        Z[base+1152] = csub(apc, bpd);
        Z[base+1728] = csub(amc, cnegi(bmd));
    }
    __syncthreads();

    // ---- Untangle + power into registers (Z region becomes pw after barrier).
    float2 pows[4];
    #pragma unroll
    for (int it = 0; it < 4; ++it) {
        int f  = tid + 256*it;
        int fm = (N_FFT - f) & (N_FFT - 1);
        pows[it] = upair(Z[OFF(f)], Z[OFF(fm)]);
    }
    float2 pnyq = make_float2(0.f, 0.f);
    if (tid == 0) { float2 znq = Z[OFF(1024)]; pnyq = upair(znq, znq); }
    __syncthreads();

    #pragma unroll
    for (int it = 0; it < 4; ++it) {
        int f = tid + 256*it;
        pw[f]             = pows[it].x;
        pw[PW_STRIDE + f] = pows[it].y;
    }
    if (tid == 0) { pw[1024] = pnyq.x; pw[PW_STRIDE + 1024] = pnyq.y; }
    __syncthreads();

    // ---- Sparse mel projection: (m,c) = (tid>>1, tid&1).
    {
        int m = tid >> 1;
        int c = tid & 1;
        int s0 = ranges[2*m];
        int e0 = ranges[2*m+1];
        const float* row = fb + m * NBINS;
        const float* pwc = pw + c * PW_STRIDE;
        float acc = 0.0f;
        for (int f = s0; f < e0; ++f) acc += row[f] * pwc[f];
        out[(((size_t)b * N_MELS + m) * T_FRAMES + t) * CH + c] = acc;
    }
}

extern "C" void kernel_launch(void* const* d_in, const int* in_sizes, int n_in,
                              void* d_out, int out_size, void* d_ws, size_t ws_size,
                              hipStream_t stream) {
    const float* x  = (const float*)d_in[0];
    const float* fb = (const float*)d_in[1];
    float* out = (float*)d_out;
    float* ws  = (float*)d_ws;

    setup_kernel<<<8 + N_MELS, 256, 0, stream>>>(fb, ws);
    mel_spec_kernel<<<BATCH * T_FRAMES, 256, 0, stream>>>(x, fb, ws, out);
}